// Round 6
// baseline (177.797 us; speedup 1.0000x reference)
//
#include <hip/hip_runtime.h>
#include <stdint.h>
#include <math.h>

// HashingDiscretizer — LDS front-end + 2-level in-row global tree.
//
// LDS (130 KB/wg): spiv[k] = {b15,b31,b47,row} (8192 x 16 B) + calibrated
// bitmask (16384 keys, 2 KB). Per element:
//   uncalibrated: 0 global scattered loads
//   calibrated:   LDS pivots -> quadrant q; 16B quadrant header
//                 {b+3,b+7,b+11} -> sub-block s; 16B leaf (4 boundaries).
//                 2 scattered instrs / 32 B total.
// qtab row = 80 floats (320 B): quadrant q at +20q floats:
//   [0..2] sub-pivots b[16q+{3,7,11}], [3] pad, [4..19] b[16q..16q+15].

#define GOLDEN   0x9E3779B9u
#define OUT_MASK ((1u << 22) - 1u)
#define NBIN  63
#define QROWF 80                 // floats per qtab row (320 B)
#define NKEY  16384              // key space covered by the bitmask
#define NPIV  8192               // key space covered by the LDS pivot table
#define MASKW (NKEY / 32)        // 512 words

typedef float fx4 __attribute__((ext_vector_type(4)));
typedef int   ix4 __attribute__((ext_vector_type(4)));

__global__ __launch_bounds__(256) void build_tables_kernel(
    const int* __restrict__ fids, const float* __restrict__ bins,
    float* __restrict__ qtab, uint4* __restrict__ gpiv,
    unsigned* __restrict__ gmask, int F)
{
    const int t = blockIdx.x * blockDim.x + threadIdx.x;
    if (t >= F * QROWF) return;
    const int r = t / QROWF;
    const int j = t - r * QROWF;
    const int q = j / 20;
    const int u = j - q * 20;
    const float* src = bins + (size_t)r * NBIN;

    int bi;
    if (u < 3)       bi = 16 * q + 4 * u + 3;   // sub-pivots e3,e7,e11
    else if (u == 3) bi = -1;                    // pad
    else             bi = 16 * q + (u - 4);      // leaves e0..e15
    float val = (bi >= 0 && bi < NBIN) ? src[bi] : INFINITY;
    if (u == 3) val = 0.0f;
    qtab[t] = val;

    if (j == 0) {
        const int k = fids[r];
        if ((unsigned)k < (unsigned)NKEY) {
            atomicOr(&gmask[k >> 5], 1u << (k & 31));
            if ((unsigned)k < (unsigned)NPIV) {
                uint4 p;
                p.x = __float_as_uint(src[15]);
                p.y = __float_as_uint(src[31]);
                p.z = __float_as_uint(src[47]);
                p.w = (unsigned)r;
                gpiv[k] = p;
            }
        }
    }
}

__device__ __forceinline__ void hd_fallback(
    int k, float v, const int* __restrict__ fids, const float* __restrict__ bins,
    int F, int fsteps, float& okey, float& oval)
{
    int lo = 0, hi = F;
    for (int s = 0; s < fsteps; ++s) {
        int  mid  = (lo + hi) >> 1;
        int  mids = min(mid, F - 1);
        int  fv   = fids[mids];
        bool valid = lo < hi;
        bool right = valid && (fv < k);
        lo = right ? mid + 1 : lo;
        hi = (valid && !right) ? mid : hi;
    }
    const int  idx_safe   = min(lo, F - 1);
    const bool calibrated = (fids[idx_safe] == k);
    const float* brow = bins + (size_t)idx_safe * NBIN;
    int blo = 0, bhi = NBIN;
    #pragma unroll
    for (int s = 0; s < 6; ++s) {
        int   mid  = (blo + bhi) >> 1;
        int   mids = min(mid, NBIN - 1);
        float bv   = brow[mids];
        bool  valid = blo < bhi;
        bool  right = valid && (bv < v);
        blo = right ? mid + 1 : blo;
        bhi = (valid && !right) ? mid : bhi;
    }
    const uint32_t h = ((uint32_t)k * GOLDEN + (uint32_t)blo) * GOLDEN;
    okey = calibrated ? (float)(h & OUT_MASK) : (float)((uint32_t)k & OUT_MASK);
    oval = calibrated ? 1.0f : v;
}

__global__ __launch_bounds__(1024) void hd_main_kernel(
    const int* __restrict__ keys, const float* __restrict__ vals,
    const int* __restrict__ fids, const float* __restrict__ bins,
    const float* __restrict__ qtab, const uint4* __restrict__ gpiv,
    const unsigned* __restrict__ gmask,
    float* __restrict__ out_keys, float* __restrict__ out_vals,
    int n, int F, int fsteps)
{
    extern __shared__ char smem[];
    uint4*    spiv  = reinterpret_cast<uint4*>(smem);
    unsigned* smask = reinterpret_cast<unsigned*>(smem + (size_t)NPIV * sizeof(uint4));

    const int tid = threadIdx.x;
    for (int i = tid; i < NPIV; i += (int)blockDim.x) spiv[i] = gpiv[i];
    if (tid < MASKW) smask[tid] = gmask[tid];
    __syncthreads();

    const int gid = blockIdx.x * blockDim.x + tid;
    const int i0 = gid * 8;
    if (i0 >= n) return;

    int   ks[8];
    float vs[8];
    const bool full = (i0 + 7 < n);
    if (full) {
        const ix4 ka = __builtin_nontemporal_load(reinterpret_cast<const ix4*>(keys + i0));
        const ix4 kb = __builtin_nontemporal_load(reinterpret_cast<const ix4*>(keys + i0 + 4));
        const fx4 va = __builtin_nontemporal_load(reinterpret_cast<const fx4*>(vals + i0));
        const fx4 vb = __builtin_nontemporal_load(reinterpret_cast<const fx4*>(vals + i0 + 4));
        ks[0]=ka.x; ks[1]=ka.y; ks[2]=ka.z; ks[3]=ka.w;
        ks[4]=kb.x; ks[5]=kb.y; ks[6]=kb.z; ks[7]=kb.w;
        vs[0]=va.x; vs[1]=va.y; vs[2]=va.z; vs[3]=va.w;
        vs[4]=vb.x; vs[5]=vb.y; vs[6]=vb.z; vs[7]=vb.w;
    } else {
        #pragma unroll
        for (int j = 0; j < 8; ++j) {
            int idx = min(i0 + j, n - 1);
            ks[j] = keys[idx];
            vs[j] = vals[idx];
        }
    }

    float ok[8], ov[8];
    #pragma unroll
    for (int j = 0; j < 8; ++j) {
        const int   k = ks[j];
        const float v = vs[j];
        if ((unsigned)k < (unsigned)NKEY) {
            const bool calib = (smask[(unsigned)k >> 5] >> (k & 31)) & 1u;
            if (calib) {
                if ((unsigned)k < (unsigned)NPIV) {
                    const uint4 p = spiv[k];
                    const float p0 = __uint_as_float(p.x);
                    const float p1 = __uint_as_float(p.y);
                    const float p2 = __uint_as_float(p.z);
                    const int q = (p0 < v) + (p1 < v) + (p2 < v);
                    const float* qbase = qtab + (size_t)p.w * QROWF + q * 20;
                    const fx4 qh = *reinterpret_cast<const fx4*>(qbase);
                    const int s = (qh.x < v) + (qh.y < v) + (qh.z < v);
                    const fx4 leaf = *reinterpret_cast<const fx4*>(qbase + 4 + 4 * s);
                    const int cnt = 16 * q + 4 * s
                        + (leaf.x < v) + (leaf.y < v) + (leaf.z < v) + (leaf.w < v);
                    const uint32_t h = ((uint32_t)k * GOLDEN + (uint32_t)cnt) * GOLDEN;
                    ok[j] = (float)(h & OUT_MASK);
                    ov[j] = 1.0f;
                } else {
                    hd_fallback(k, v, fids, bins, F, fsteps, ok[j], ov[j]);
                }
            } else {
                ok[j] = (float)((uint32_t)k & OUT_MASK);
                ov[j] = v;
            }
        } else {
            hd_fallback(k, v, fids, bins, F, fsteps, ok[j], ov[j]);
        }
    }

    if (full) {
        fx4 a, b;
        a.x=ok[0]; a.y=ok[1]; a.z=ok[2]; a.w=ok[3];
        b.x=ok[4]; b.y=ok[5]; b.z=ok[6]; b.w=ok[7];
        __builtin_nontemporal_store(a, reinterpret_cast<fx4*>(out_keys + i0));
        __builtin_nontemporal_store(b, reinterpret_cast<fx4*>(out_keys + i0 + 4));
        a.x=ov[0]; a.y=ov[1]; a.z=ov[2]; a.w=ov[3];
        b.x=ov[4]; b.y=ov[5]; b.z=ov[6]; b.w=ov[7];
        __builtin_nontemporal_store(a, reinterpret_cast<fx4*>(out_vals + i0));
        __builtin_nontemporal_store(b, reinterpret_cast<fx4*>(out_vals + i0 + 4));
    } else {
        for (int j = 0; j < 8 && i0 + j < n; ++j) {
            out_keys[i0 + j] = ok[j];
            out_vals[i0 + j] = ov[j];
        }
    }
}

// Pure binary-search kernel: used only if LDS or workspace is insufficient.
__global__ __launch_bounds__(256) void hd_simple_kernel(
    const int* __restrict__ keys, const float* __restrict__ vals,
    const int* __restrict__ fids, const float* __restrict__ bins,
    float* __restrict__ out_keys, float* __restrict__ out_vals,
    int n, int F, int fsteps)
{
    const int gid = blockIdx.x * blockDim.x + threadIdx.x;
    const int i0 = gid * 4;
    if (i0 >= n) return;
    #pragma unroll
    for (int j = 0; j < 4; ++j) {
        int idx = min(i0 + j, n - 1);
        float okey, oval;
        hd_fallback(keys[idx], vals[idx], fids, bins, F, fsteps, okey, oval);
        if (i0 + j < n) { out_keys[i0 + j] = okey; out_vals[i0 + j] = oval; }
    }
}

extern "C" void kernel_launch(void* const* d_in, const int* in_sizes, int n_in,
                              void* d_out, int out_size, void* d_ws, size_t ws_size,
                              hipStream_t stream) {
    const int*   keys = (const int*)d_in[0];
    const float* vals = (const float*)d_in[1];
    const int*   fids = (const int*)d_in[2];
    const float* bins = (const float*)d_in[3];

    const int n = in_sizes[0];
    const int F = in_sizes[2];

    int fsteps = 0;
    while ((1 << fsteps) < F + 1) ++fsteps;

    float* out_keys = (float*)d_out;
    float* out_vals = (float*)d_out + n;

    // Workspace: qtab (F*80 f32) | gpiv (NPIV uint4) | gmask (MASKW u32)
    const size_t qtab_bytes = (size_t)F * QROWF * sizeof(float);
    const size_t ws_need    = qtab_bytes + (size_t)NPIV * 16 + (size_t)MASKW * 4;
    const size_t lds_bytes  = (size_t)NPIV * 16 + (size_t)MASKW * 4;  // 133120

    int max_lds = 0;
    hipDeviceGetAttribute(&max_lds, hipDeviceAttributeMaxSharedMemoryPerBlock, 0);

    const bool fast = (ws_size >= ws_need) && ((size_t)max_lds >= lds_bytes) &&
                      (in_sizes[3] == F * NBIN);

    if (fast) {
        float*    qtab  = (float*)d_ws;
        uint4*    gpiv  = (uint4*)((char*)d_ws + qtab_bytes);
        unsigned* gmask = (unsigned*)((char*)gpiv + (size_t)NPIV * 16);

        hipMemsetAsync(gmask, 0, (size_t)MASKW * 4, stream);
        build_tables_kernel<<<(F * QROWF + 255) / 256, 256, 0, stream>>>(
            fids, bins, qtab, gpiv, gmask, F);

        (void)hipFuncSetAttribute(
            reinterpret_cast<const void*>(hd_main_kernel),
            hipFuncAttributeMaxDynamicSharedMemorySize, (int)lds_bytes);

        const int threads = 1024;
        const int grid = (n + threads * 8 - 1) / (threads * 8);
        hd_main_kernel<<<grid, threads, lds_bytes, stream>>>(
            keys, vals, fids, bins, qtab, gpiv, gmask,
            out_keys, out_vals, n, F, fsteps);
    } else {
        const int threads = 256;
        const int grid = (n + threads * 4 - 1) / (threads * 4);
        hd_simple_kernel<<<grid, threads, 0, stream>>>(
            keys, vals, fids, bins, out_keys, out_vals, n, F, fsteps);
    }
}

// Round 7
// 177.721 us; speedup vs baseline: 1.0004x; 1.0004x over previous
//
#include <hip/hip_runtime.h>
#include <stdint.h>
#include <math.h>

// HashingDiscretizer — LDS tercile front-end, 1 global gather round, 2 blk/CU.
//
// LDS (66 KB/wg): spiv[k] = {b20,b41} f32 (8192 x 8 B = 64 KB) + calibrated
// bitmask (16384 keys, 2 KB). Per element:
//   uncalibrated: 0 global scattered loads
//   calibrated:   LDS pivots -> tercile t; 6 INDEPENDENT 16B loads of the
//                 24-float section (21 boundaries + 3 inf pads); count.
// qtab row = 72 floats (288 B), key-indexed; section t at +24t floats.

#define GOLDEN   0x9E3779B9u
#define OUT_MASK ((1u << 22) - 1u)
#define NBIN  63
#define SECL  21                 // boundaries per section
#define SECP  24                 // padded section length (floats)
#define QROWF 72                 // floats per qtab row (288 B)
#define NKEY  16384              // key space covered by the bitmask
#define NPIV  8192               // key space covered by the LDS pivot table
#define MASKW (NKEY / 32)        // 512 words

typedef float fx4 __attribute__((ext_vector_type(4)));
typedef int   ix4 __attribute__((ext_vector_type(4)));
typedef float fx2 __attribute__((ext_vector_type(2)));

__global__ __launch_bounds__(256) void build_tables_kernel(
    const int* __restrict__ fids, const float* __restrict__ bins,
    float* __restrict__ qtab, fx2* __restrict__ gpiv,
    unsigned* __restrict__ gmask, int F)
{
    const int t = blockIdx.x * blockDim.x + threadIdx.x;
    if (t >= F * QROWF) return;
    const int r = t / QROWF;
    const int j = t - r * QROWF;
    const int k = fids[r];

    if (j == 0 && (unsigned)k < (unsigned)NKEY) {
        atomicOr(&gmask[k >> 5], 1u << (k & 31));
    }
    if ((unsigned)k >= (unsigned)NPIV) return;

    const float* src = bins + (size_t)r * NBIN;
    const int q = j / SECP;          // section 0..2
    const int u = j - q * SECP;      // slot in section
    const int bi = SECL * q + u;     // boundary index if u < SECL
    qtab[(size_t)k * QROWF + j] = (u < SECL && bi < NBIN) ? src[bi] : INFINITY;

    if (j == 0) {
        fx2 p; p.x = src[20]; p.y = src[41];
        gpiv[k] = p;
    }
}

__device__ __forceinline__ void hd_fallback(
    int k, float v, const int* __restrict__ fids, const float* __restrict__ bins,
    int F, int fsteps, float& okey, float& oval)
{
    int lo = 0, hi = F;
    for (int s = 0; s < fsteps; ++s) {
        int  mid  = (lo + hi) >> 1;
        int  mids = min(mid, F - 1);
        int  fv   = fids[mids];
        bool valid = lo < hi;
        bool right = valid && (fv < k);
        lo = right ? mid + 1 : lo;
        hi = (valid && !right) ? mid : hi;
    }
    const int  idx_safe   = min(lo, F - 1);
    const bool calibrated = (fids[idx_safe] == k);
    const float* brow = bins + (size_t)idx_safe * NBIN;
    int blo = 0, bhi = NBIN;
    #pragma unroll
    for (int s = 0; s < 6; ++s) {
        int   mid  = (blo + bhi) >> 1;
        int   mids = min(mid, NBIN - 1);
        float bv   = brow[mids];
        bool  valid = blo < bhi;
        bool  right = valid && (bv < v);
        blo = right ? mid + 1 : blo;
        bhi = (valid && !right) ? mid : bhi;
    }
    const uint32_t h = ((uint32_t)k * GOLDEN + (uint32_t)blo) * GOLDEN;
    okey = calibrated ? (float)(h & OUT_MASK) : (float)((uint32_t)k & OUT_MASK);
    oval = calibrated ? 1.0f : v;
}

__global__ __launch_bounds__(1024) void hd_main_kernel(
    const int* __restrict__ keys, const float* __restrict__ vals,
    const int* __restrict__ fids, const float* __restrict__ bins,
    const float* __restrict__ qtab, const fx2* __restrict__ gpiv,
    const unsigned* __restrict__ gmask,
    float* __restrict__ out_keys, float* __restrict__ out_vals,
    int n, int F, int fsteps)
{
    extern __shared__ char smem[];
    fx2*      spiv  = reinterpret_cast<fx2*>(smem);
    unsigned* smask = reinterpret_cast<unsigned*>(smem + (size_t)NPIV * sizeof(fx2));

    const int tid = threadIdx.x;
    for (int i = tid; i < NPIV; i += (int)blockDim.x) spiv[i] = gpiv[i];
    if (tid < MASKW) smask[tid] = gmask[tid];
    __syncthreads();

    const int gid = blockIdx.x * blockDim.x + tid;
    const int i0 = gid * 8;
    if (i0 >= n) return;

    int   ks[8];
    float vs[8];
    const bool full = (i0 + 7 < n);
    if (full) {
        const ix4 ka = __builtin_nontemporal_load(reinterpret_cast<const ix4*>(keys + i0));
        const ix4 kb = __builtin_nontemporal_load(reinterpret_cast<const ix4*>(keys + i0 + 4));
        const fx4 va = __builtin_nontemporal_load(reinterpret_cast<const fx4*>(vals + i0));
        const fx4 vb = __builtin_nontemporal_load(reinterpret_cast<const fx4*>(vals + i0 + 4));
        ks[0]=ka.x; ks[1]=ka.y; ks[2]=ka.z; ks[3]=ka.w;
        ks[4]=kb.x; ks[5]=kb.y; ks[6]=kb.z; ks[7]=kb.w;
        vs[0]=va.x; vs[1]=va.y; vs[2]=va.z; vs[3]=va.w;
        vs[4]=vb.x; vs[5]=vb.y; vs[6]=vb.z; vs[7]=vb.w;
    } else {
        #pragma unroll
        for (int j = 0; j < 8; ++j) {
            int idx = min(i0 + j, n - 1);
            ks[j] = keys[idx];
            vs[j] = vals[idx];
        }
    }

    float ok[8], ov[8];
    #pragma unroll
    for (int j = 0; j < 8; ++j) {
        const int   k = ks[j];
        const float v = vs[j];
        if ((unsigned)k < (unsigned)NKEY) {
            const bool calib = (smask[(unsigned)k >> 5] >> (k & 31)) & 1u;
            if (calib) {
                if ((unsigned)k < (unsigned)NPIV) {
                    const fx2 p = spiv[k];
                    const int t = (p.x < v) + (p.y < v);
                    const fx4* sec = reinterpret_cast<const fx4*>(
                        qtab + (size_t)(unsigned)k * QROWF + t * SECP);
                    const fx4 b0 = sec[0], b1 = sec[1], b2 = sec[2],
                              b3 = sec[3], b4 = sec[4], b5 = sec[5];
                    const int cnt = SECL * t
                        + (b0.x < v) + (b0.y < v) + (b0.z < v) + (b0.w < v)
                        + (b1.x < v) + (b1.y < v) + (b1.z < v) + (b1.w < v)
                        + (b2.x < v) + (b2.y < v) + (b2.z < v) + (b2.w < v)
                        + (b3.x < v) + (b3.y < v) + (b3.z < v) + (b3.w < v)
                        + (b4.x < v) + (b4.y < v) + (b4.z < v) + (b4.w < v)
                        + (b5.x < v) + (b5.y < v) + (b5.z < v) + (b5.w < v);
                    const uint32_t h = ((uint32_t)k * GOLDEN + (uint32_t)cnt) * GOLDEN;
                    ok[j] = (float)(h & OUT_MASK);
                    ov[j] = 1.0f;
                } else {
                    hd_fallback(k, v, fids, bins, F, fsteps, ok[j], ov[j]);
                }
            } else {
                ok[j] = (float)((uint32_t)k & OUT_MASK);
                ov[j] = v;
            }
        } else {
            hd_fallback(k, v, fids, bins, F, fsteps, ok[j], ov[j]);
        }
    }

    if (full) {
        fx4 a, b;
        a.x=ok[0]; a.y=ok[1]; a.z=ok[2]; a.w=ok[3];
        b.x=ok[4]; b.y=ok[5]; b.z=ok[6]; b.w=ok[7];
        __builtin_nontemporal_store(a, reinterpret_cast<fx4*>(out_keys + i0));
        __builtin_nontemporal_store(b, reinterpret_cast<fx4*>(out_keys + i0 + 4));
        a.x=ov[0]; a.y=ov[1]; a.z=ov[2]; a.w=ov[3];
        b.x=ov[4]; b.y=ov[5]; b.z=ov[6]; b.w=ov[7];
        __builtin_nontemporal_store(a, reinterpret_cast<fx4*>(out_vals + i0));
        __builtin_nontemporal_store(b, reinterpret_cast<fx4*>(out_vals + i0 + 4));
    } else {
        for (int j = 0; j < 8 && i0 + j < n; ++j) {
            out_keys[i0 + j] = ok[j];
            out_vals[i0 + j] = ov[j];
        }
    }
}

// Pure binary-search kernel: used only if LDS or workspace is insufficient.
__global__ __launch_bounds__(256) void hd_simple_kernel(
    const int* __restrict__ keys, const float* __restrict__ vals,
    const int* __restrict__ fids, const float* __restrict__ bins,
    float* __restrict__ out_keys, float* __restrict__ out_vals,
    int n, int F, int fsteps)
{
    const int gid = blockIdx.x * blockDim.x + threadIdx.x;
    const int i0 = gid * 4;
    if (i0 >= n) return;
    #pragma unroll
    for (int j = 0; j < 4; ++j) {
        int idx = min(i0 + j, n - 1);
        float okey, oval;
        hd_fallback(keys[idx], vals[idx], fids, bins, F, fsteps, okey, oval);
        if (i0 + j < n) { out_keys[i0 + j] = okey; out_vals[i0 + j] = oval; }
    }
}

extern "C" void kernel_launch(void* const* d_in, const int* in_sizes, int n_in,
                              void* d_out, int out_size, void* d_ws, size_t ws_size,
                              hipStream_t stream) {
    const int*   keys = (const int*)d_in[0];
    const float* vals = (const float*)d_in[1];
    const int*   fids = (const int*)d_in[2];
    const float* bins = (const float*)d_in[3];

    const int n = in_sizes[0];
    const int F = in_sizes[2];

    int fsteps = 0;
    while ((1 << fsteps) < F + 1) ++fsteps;

    float* out_keys = (float*)d_out;
    float* out_vals = (float*)d_out + n;

    // Workspace: qtab (NPIV*72 f32) | gpiv (NPIV fx2) | gmask (MASKW u32)
    const size_t qtab_bytes = (size_t)NPIV * QROWF * sizeof(float);
    const size_t gpiv_bytes = (size_t)NPIV * sizeof(fx2);
    const size_t ws_need    = qtab_bytes + gpiv_bytes + (size_t)MASKW * 4;
    const size_t lds_bytes  = gpiv_bytes + (size_t)MASKW * 4;  // 67584 B

    int max_lds = 0;
    hipDeviceGetAttribute(&max_lds, hipDeviceAttributeMaxSharedMemoryPerBlock, 0);

    const bool fast = (ws_size >= ws_need) && ((size_t)max_lds >= lds_bytes) &&
                      (in_sizes[3] == F * NBIN);

    if (fast) {
        float*    qtab  = (float*)d_ws;
        fx2*      gpiv  = (fx2*)((char*)d_ws + qtab_bytes);
        unsigned* gmask = (unsigned*)((char*)gpiv + gpiv_bytes);

        hipMemsetAsync(gmask, 0, (size_t)MASKW * 4, stream);
        build_tables_kernel<<<(F * QROWF + 255) / 256, 256, 0, stream>>>(
            fids, bins, qtab, gpiv, gmask, F);

        (void)hipFuncSetAttribute(
            reinterpret_cast<const void*>(hd_main_kernel),
            hipFuncAttributeMaxDynamicSharedMemorySize, (int)lds_bytes);

        const int threads = 1024;
        const int grid = (n + threads * 8 - 1) / (threads * 8);
        hd_main_kernel<<<grid, threads, lds_bytes, stream>>>(
            keys, vals, fids, bins, qtab, gpiv, gmask,
            out_keys, out_vals, n, F, fsteps);
    } else {
        const int threads = 256;
        const int grid = (n + threads * 4 - 1) / (threads * 4);
        hd_simple_kernel<<<grid, threads, 0, stream>>>(
            keys, vals, fids, bins, out_keys, out_vals, n, F, fsteps);
    }
}